// Round 1
// baseline (17.515 us; speedup 1.0000x reference)
//
#include <hip/hip_runtime.h>
#include <math.h>

#define TPB 256
#define TOK 4
#define TILE (TPB * TOK)        // 1024 tokens per block
#define HALO 14                 // MAX_SPAN_WIDTH - 1
#define WIN (TOK + 2 * HALO)    // 32-value per-thread window
#define NEGINF (-10000.0f)
#define SENT (-1.0e30f)         // out-of-row sentinel (invalid spans lose every max)

// For width W, combine sparse-table min levels (K = 2^floor(log2 W)) to get
// span mins Q[u] for span starts s = 15-W+u (u = 0..W+2), covering exactly the
// spans containing the thread's 4 tokens. Then per-token max over its W starts,
// sharing the interior "core" max across the 4 tokens. All indices compile-time.
template <int W>
__device__ __forceinline__ void do_width(const float (&P2)[WIN - 1],
                                         const float (&P4)[WIN - 3],
                                         const float (&P8)[WIN - 7],
                                         float wt, float &b0, float &b1,
                                         float &b2, float &b3) {
  constexpr int K = (W < 4) ? 2 : ((W < 8) ? 4 : 8);
  float Q[W + 3];
#pragma unroll
  for (int u = 0; u < W + 3; ++u) {
    const int s = (HALO + 1) - W + u;  // 15 - W + u
    if constexpr (K == 2)
      Q[u] = fminf(P2[s], P2[s + (W - K)]);
    else if constexpr (K == 4)
      Q[u] = fminf(P4[s], P4[s + (W - K)]);
    else
      Q[u] = fminf(P8[s], P8[s + (W - K)]);
  }
  // token j needs max over Q[j .. j+W-1]
  float m0, m1, m2, m3;
  if constexpr (W == 2) {
    m0 = fmaxf(Q[0], Q[1]);
    m1 = fmaxf(Q[1], Q[2]);
    m2 = fmaxf(Q[2], Q[3]);
    m3 = fmaxf(Q[3], Q[4]);
  } else if constexpr (W == 3) {
    m0 = fmaxf(Q[0], fmaxf(Q[1], Q[2]));
    m1 = fmaxf(Q[1], fmaxf(Q[2], Q[3]));
    m2 = fmaxf(Q[2], fmaxf(Q[3], Q[4]));
    m3 = fmaxf(Q[3], fmaxf(Q[4], Q[5]));
  } else {
    float core = Q[3];  // core = max Q[3..W-1] (empty loop for W==4)
#pragma unroll
    for (int u = 4; u < W; ++u) core = fmaxf(core, Q[u]);
    const float q2c = fmaxf(Q[2], core);
    const float dW = fmaxf(Q[W], Q[W + 1]);
    m0 = fmaxf(fmaxf(Q[0], Q[1]), q2c);        // u in [0, W-1]
    m1 = fmaxf(fmaxf(Q[1], Q[W]), q2c);        // u in [1, W]
    m2 = fmaxf(q2c, dW);                       // u in [2, W+1]
    m3 = fmaxf(fmaxf(core, Q[W + 2]), dW);     // u in [3, W+2]
  }
  b0 = fmaxf(b0, m0 * wt);
  b1 = fmaxf(b1, m1 * wt);
  b2 = fmaxf(b2, m2 * wt);
  b3 = fmaxf(b3, m3 * wt);
}

__global__ __launch_bounds__(TPB) void span_kernel(
    const float *__restrict__ ts, const int *__restrict__ mask,
    const float *__restrict__ wlog, const float *__restrict__ gamma_p,
    float *__restrict__ out, int N, int tiles_per_row) {
  __shared__ __align__(16) float sm[TILE + 2 * HALO];
  const int row = blockIdx.x / tiles_per_row;
  const int t0 = (blockIdx.x % tiles_per_row) * TILE;
  const float *tsrow = ts + (size_t)row * N;
  const int *mrow = mask + (size_t)row * N;

  // stage masked scores (+halo) into LDS; out-of-row = sentinel
  for (int k = threadIdx.x; k < TILE + 2 * HALO; k += TPB) {
    const int g = t0 - HALO + k;
    float v = SENT;
    if (g >= 0 && g < N) v = (mrow[g] == 0) ? NEGINF : tsrow[g];
    sm[k] = v;
  }

  // softmax over the 15 width logits (redundant per thread; only idx 0..13 used)
  float wt[14];
  {
    float e[15];
    float mx = -3.4e38f;
#pragma unroll
    for (int i = 0; i < 15; ++i) {
      e[i] = wlog[i];
      mx = fmaxf(mx, e[i]);
    }
    float ssum = 0.0f;
#pragma unroll
    for (int i = 0; i < 15; ++i) {
      e[i] = expf(e[i] - mx);
      ssum += e[i];
    }
    const float inv = 1.0f / ssum;
#pragma unroll
    for (int i = 0; i < 14; ++i) wt[i] = e[i] * inv;
  }
  const float gamma = *gamma_p;

  __syncthreads();

  // per-thread 32-value window: tokens t0+4*tid .. +3 at win[14..17]
  const int base = threadIdx.x * TOK;
  float win[WIN];
#pragma unroll
  for (int q = 0; q < WIN / 4; ++q) {
    const float4 v = *reinterpret_cast<const float4 *>(&sm[base + 4 * q]);
    win[4 * q + 0] = v.x;
    win[4 * q + 1] = v.y;
    win[4 * q + 2] = v.z;
    win[4 * q + 3] = v.w;
  }

  // sparse-table min levels (registers, static indices only)
  float P2[WIN - 1], P4[WIN - 3], P8[WIN - 7];
#pragma unroll
  for (int x = 0; x < WIN - 1; ++x) P2[x] = fminf(win[x], win[x + 1]);
#pragma unroll
  for (int x = 0; x < WIN - 3; ++x) P4[x] = fminf(P2[x], P2[x + 2]);
#pragma unroll
  for (int x = 0; x < WIN - 7; ++x) P8[x] = fminf(P4[x], P4[x + 4]);

  // width-1 boost = masked score itself
  float b0 = win[HALO + 0], b1 = win[HALO + 1], b2 = win[HALO + 2],
        b3 = win[HALO + 3];

  do_width<2>(P2, P4, P8, wt[0], b0, b1, b2, b3);
  do_width<3>(P2, P4, P8, wt[1], b0, b1, b2, b3);
  do_width<4>(P2, P4, P8, wt[2], b0, b1, b2, b3);
  do_width<5>(P2, P4, P8, wt[3], b0, b1, b2, b3);
  do_width<6>(P2, P4, P8, wt[4], b0, b1, b2, b3);
  do_width<7>(P2, P4, P8, wt[5], b0, b1, b2, b3);
  do_width<8>(P2, P4, P8, wt[6], b0, b1, b2, b3);
  do_width<9>(P2, P4, P8, wt[7], b0, b1, b2, b3);
  do_width<10>(P2, P4, P8, wt[8], b0, b1, b2, b3);
  do_width<11>(P2, P4, P8, wt[9], b0, b1, b2, b3);
  do_width<12>(P2, P4, P8, wt[10], b0, b1, b2, b3);
  do_width<13>(P2, P4, P8, wt[11], b0, b1, b2, b3);
  do_width<14>(P2, P4, P8, wt[12], b0, b1, b2, b3);
  do_width<15>(P2, P4, P8, wt[13], b0, b1, b2, b3);

  const int gtok = t0 + base;
  const float4 tv = *reinterpret_cast<const float4 *>(&tsrow[gtok]);
  float4 o;
  o.x = tv.x + gamma * b0;
  o.y = tv.y + gamma * b1;
  o.z = tv.z + gamma * b2;
  o.w = tv.w + gamma * b3;
  *reinterpret_cast<float4 *>(&out[(size_t)row * N + gtok]) = o;
}

extern "C" void kernel_launch(void *const *d_in, const int *in_sizes, int n_in,
                              void *d_out, int out_size, void *d_ws,
                              size_t ws_size, hipStream_t stream) {
  const float *ts = (const float *)d_in[0];
  const int *mask = (const int *)d_in[1];
  const float *wlog = (const float *)d_in[2];
  const float *gamma_p = (const float *)d_in[3];
  float *out = (float *)d_out;
  const int N = 8192;                 // fixed problem shape (B=256, N=8192)
  const int B = in_sizes[0] / N;
  const int tiles = N / TILE;         // 8
  span_kernel<<<dim3(B * tiles), dim3(TPB), 0, stream>>>(ts, mask, wlog,
                                                         gamma_p, out, N,
                                                         tiles);
}

// Round 2
// 14.809 us; speedup vs baseline: 1.1827x; 1.1827x over previous
//
#include <hip/hip_runtime.h>
#include <math.h>

#define TPB 256
#define TOK 4
#define TILE (TPB * TOK)        // 1024 tokens per block
#define HALO 14                 // MAX_SPAN_WIDTH - 1
#define WIN (TOK + 2 * HALO)    // 32-value per-thread window
#define NEGINF (-10000.0f)
#define SENT (-1.0e30f)         // out-of-row sentinel (invalid spans lose every max)

// For width W, build span-mins Q[u] (span start s = 15-W+u in window coords)
// from one sparse-table level Pk (K = 2^floor(log2 W)); token j needs
// max over Q[j .. j+W-1]. All indices compile-time -> registers only.
template <int W, int L>
__device__ __forceinline__ void do_width(const float (&Pk)[L], float wt,
                                         float &b0, float &b1, float &b2,
                                         float &b3) {
  constexpr int K = (W < 4) ? 2 : ((W < 8) ? 4 : 8);
  float Q[W + 3];
#pragma unroll
  for (int u = 0; u < W + 3; ++u) {
    const int s = (HALO + 1) - W + u;  // 15 - W + u
    if constexpr (W == K)
      Q[u] = Pk[s];
    else
      Q[u] = fminf(Pk[s], Pk[s + (W - K)]);
  }
  float m0, m1, m2, m3;
  if constexpr (W == 2) {
    m0 = fmaxf(Q[0], Q[1]);
    m1 = fmaxf(Q[1], Q[2]);
    m2 = fmaxf(Q[2], Q[3]);
    m3 = fmaxf(Q[3], Q[4]);
  } else if constexpr (W == 3) {
    m0 = fmaxf(Q[0], fmaxf(Q[1], Q[2]));
    m1 = fmaxf(Q[1], fmaxf(Q[2], Q[3]));
    m2 = fmaxf(Q[2], fmaxf(Q[3], Q[4]));
    m3 = fmaxf(Q[3], fmaxf(Q[4], Q[5]));
  } else {
    float core = Q[3];  // max Q[3..W-1]; empty tail loop for W==4
#pragma unroll
    for (int u = 4; u < W; ++u) core = fmaxf(core, Q[u]);
    const float q2c = fmaxf(Q[2], core);
    const float dW = fmaxf(Q[W], Q[W + 1]);
    m0 = fmaxf(fmaxf(Q[0], Q[1]), q2c);     // u in [0, W-1]
    m1 = fmaxf(fmaxf(Q[1], Q[W]), q2c);     // u in [1, W]
    m2 = fmaxf(q2c, dW);                    // u in [2, W+1]
    m3 = fmaxf(fmaxf(core, Q[W + 2]), dW);  // u in [3, W+2]
  }
  b0 = fmaxf(b0, m0 * wt);
  b1 = fmaxf(b1, m1 * wt);
  b2 = fmaxf(b2, m2 * wt);
  b3 = fmaxf(b3, m3 * wt);
}

__global__ __launch_bounds__(TPB) void span_kernel(
    const float *__restrict__ ts, const int *__restrict__ mask,
    const float *__restrict__ wlog, const float *__restrict__ gamma_p,
    float *__restrict__ out, int N, int tiles_per_row) {
  __shared__ __align__(16) float sm[TILE + 2 * HALO];
  __shared__ float swt[15];  // 14 softmax weights + gamma at [14]
  const int tid = threadIdx.x;
  const int row = blockIdx.x / tiles_per_row;
  const int t0 = (blockIdx.x % tiles_per_row) * TILE;
  const float *tsrow = ts + (size_t)row * N;
  const int *mrow = mask + (size_t)row * N;

  // ---- staging: one int4 + one float4 per thread for the main tile ----
  const int j = tid * TOK;  // 0..1020, 16B-aligned in both global and LDS-read
  const int g = t0 + j;
  const int4 mv = *reinterpret_cast<const int4 *>(&mrow[g]);
  const float4 tv = *reinterpret_cast<const float4 *>(&tsrow[g]);
  {
    float2 w01, w23;
    w01.x = mv.x ? tv.x : NEGINF;
    w01.y = mv.y ? tv.y : NEGINF;
    w23.x = mv.z ? tv.z : NEGINF;
    w23.y = mv.w ? tv.w : NEGINF;
    *reinterpret_cast<float2 *>(&sm[HALO + j]) = w01;      // 8B-aligned
    *reinterpret_cast<float2 *>(&sm[HALO + j + 2]) = w23;  // 8B-aligned
  }
  // halo: first 14 threads fill both edges (out-of-row -> sentinel)
  if (tid < HALO) {
    const int gl = t0 - HALO + tid;
    sm[tid] = (gl >= 0) ? (mrow[gl] ? tsrow[gl] : NEGINF) : SENT;
    const int gr = t0 + TILE + tid;
    sm[TILE + HALO + tid] = (gr < N) ? (mrow[gr] ? tsrow[gr] : NEGINF) : SENT;
  }
  // softmax of width logits: ONE thread per block (last wave, avoids the
  // halo threads' divergence)
  if (tid == TPB - 1) {
    float e[15], mx = -3.4e38f;
#pragma unroll
    for (int i = 0; i < 15; ++i) {
      e[i] = wlog[i];
      mx = fmaxf(mx, e[i]);
    }
    float ssum = 0.0f;
#pragma unroll
    for (int i = 0; i < 15; ++i) {
      e[i] = expf(e[i] - mx);
      ssum += e[i];
    }
    const float inv = 1.0f / ssum;
#pragma unroll
    for (int i = 0; i < 14; ++i) swt[i] = e[i] * inv;
    swt[14] = *gamma_p;
  }
  __syncthreads();

  // ---- per-thread 32-value window (8x ds_read_b128, uniform stride) ----
  float win[WIN];
#pragma unroll
  for (int q = 0; q < WIN / 4; ++q) {
    const float4 v = *reinterpret_cast<const float4 *>(&sm[j + 4 * q]);
    win[4 * q + 0] = v.x;
    win[4 * q + 1] = v.y;
    win[4 * q + 2] = v.z;
    win[4 * q + 3] = v.w;
  }
  float b0 = win[HALO + 0], b1 = win[HALO + 1], b2 = win[HALO + 2],
        b3 = win[HALO + 3];

  // ---- pressure-ordered sparse-table: consume each level before the next ----
  float P2[WIN - 1];
#pragma unroll
  for (int x = 0; x < WIN - 1; ++x) P2[x] = fminf(win[x], win[x + 1]);
  do_width<2>(P2, swt[0], b0, b1, b2, b3);
  do_width<3>(P2, swt[1], b0, b1, b2, b3);

  float P4[WIN - 3];
#pragma unroll
  for (int x = 0; x < WIN - 3; ++x) P4[x] = fminf(P2[x], P2[x + 2]);
  do_width<4>(P4, swt[2], b0, b1, b2, b3);
  do_width<5>(P4, swt[3], b0, b1, b2, b3);
  do_width<6>(P4, swt[4], b0, b1, b2, b3);
  do_width<7>(P4, swt[5], b0, b1, b2, b3);

  float P8[WIN - 7];
#pragma unroll
  for (int x = 0; x < WIN - 7; ++x) P8[x] = fminf(P4[x], P4[x + 4]);
  do_width<8>(P8, swt[6], b0, b1, b2, b3);
  do_width<9>(P8, swt[7], b0, b1, b2, b3);
  do_width<10>(P8, swt[8], b0, b1, b2, b3);
  do_width<11>(P8, swt[9], b0, b1, b2, b3);
  do_width<12>(P8, swt[10], b0, b1, b2, b3);
  do_width<13>(P8, swt[11], b0, b1, b2, b3);
  do_width<14>(P8, swt[12], b0, b1, b2, b3);
  do_width<15>(P8, swt[13], b0, b1, b2, b3);

  // ---- output: raw scores kept in registers from staging ----
  const float gamma = swt[14];
  float4 o;
  o.x = tv.x + gamma * b0;
  o.y = tv.y + gamma * b1;
  o.z = tv.z + gamma * b2;
  o.w = tv.w + gamma * b3;
  *reinterpret_cast<float4 *>(&out[(size_t)row * N + g]) = o;
}

extern "C" void kernel_launch(void *const *d_in, const int *in_sizes, int n_in,
                              void *d_out, int out_size, void *d_ws,
                              size_t ws_size, hipStream_t stream) {
  const float *ts = (const float *)d_in[0];
  const int *mask = (const int *)d_in[1];
  const float *wlog = (const float *)d_in[2];
  const float *gamma_p = (const float *)d_in[3];
  float *out = (float *)d_out;
  const int N = 8192;          // fixed problem shape (B=256, N=8192)
  const int B = in_sizes[0] / N;
  const int tiles = N / TILE;  // 8
  span_kernel<<<dim3(B * tiles), dim3(TPB), 0, stream>>>(ts, mask, wlog,
                                                         gamma_p, out, N,
                                                         tiles);
}

// Round 3
// 14.779 us; speedup vs baseline: 1.1851x; 1.0020x over previous
//
#include <hip/hip_runtime.h>
#include <math.h>

#define TPB 256
#define TOK 4
#define TILE (TPB * TOK)        // 1024 tokens per block
#define HALO 14                 // MAX_SPAN_WIDTH - 1
#define WIN (TOK + 2 * HALO)    // 32-value per-thread window
#define NEGINF (-10000.0f)
#define SENT (-1.0e30f)         // out-of-row sentinel (invalid spans lose every max)

// A[] holds (in place) the sparse-table level K = 2^floor(log2 W) when called.
// Span mins Q[u] for span start s = 15-W+u; token j needs max over Q[j..j+W-1].
// All indices compile-time -> registers only.
template <int W>
__device__ __forceinline__ void do_width(const float (&A)[WIN], float wt,
                                         float &b0, float &b1, float &b2,
                                         float &b3) {
  constexpr int K = (W < 4) ? 2 : ((W < 8) ? 4 : 8);
  float Q[W + 3];
#pragma unroll
  for (int u = 0; u < W + 3; ++u) {
    const int s = (HALO + 1) - W + u;  // 15 - W + u
    if constexpr (W == K)
      Q[u] = A[s];
    else
      Q[u] = fminf(A[s], A[s + (W - K)]);
  }
  float m0, m1, m2, m3;
  if constexpr (W == 2) {
    m0 = fmaxf(Q[0], Q[1]);
    m1 = fmaxf(Q[1], Q[2]);
    m2 = fmaxf(Q[2], Q[3]);
    m3 = fmaxf(Q[3], Q[4]);
  } else if constexpr (W == 3) {
    m0 = fmaxf(Q[0], fmaxf(Q[1], Q[2]));
    m1 = fmaxf(Q[1], fmaxf(Q[2], Q[3]));
    m2 = fmaxf(Q[2], fmaxf(Q[3], Q[4]));
    m3 = fmaxf(Q[3], fmaxf(Q[4], Q[5]));
  } else {
    float core = Q[3];  // max Q[3..W-1]; empty tail loop for W==4
#pragma unroll
    for (int u = 4; u < W; ++u) core = fmaxf(core, Q[u]);
    const float q2c = fmaxf(Q[2], core);
    const float dW = fmaxf(Q[W], Q[W + 1]);
    m0 = fmaxf(fmaxf(Q[0], Q[1]), q2c);     // u in [0, W-1]
    m1 = fmaxf(fmaxf(Q[1], Q[W]), q2c);     // u in [1, W]
    m2 = fmaxf(q2c, dW);                    // u in [2, W+1]
    m3 = fmaxf(fmaxf(core, Q[W + 2]), dW);  // u in [3, W+2]
  }
  b0 = fmaxf(b0, m0 * wt);
  b1 = fmaxf(b1, m1 * wt);
  b2 = fmaxf(b2, m2 * wt);
  b3 = fmaxf(b3, m3 * wt);
}

__global__ __launch_bounds__(TPB, 5) void span_kernel(
    const float *__restrict__ ts, const int *__restrict__ mask,
    const float *__restrict__ wlog, const float *__restrict__ gamma_p,
    float *__restrict__ out, int N, int tiles_per_row) {
  __shared__ __align__(16) float sm[TILE + 2 * HALO];
  __shared__ float swt[15];  // 14 softmax weights + gamma at [14]
  const int tid = threadIdx.x;
  const int row = blockIdx.x / tiles_per_row;
  const int t0 = (blockIdx.x % tiles_per_row) * TILE;
  const float *tsrow = ts + (size_t)row * N;
  const int *mrow = mask + (size_t)row * N;

  // ---- staging: one int4 + one float4 per thread for the main tile ----
  const int j = tid * TOK;  // 0..1020
  const int g = t0 + j;
  const int4 mv = *reinterpret_cast<const int4 *>(&mrow[g]);
  const float4 tv = *reinterpret_cast<const float4 *>(&tsrow[g]);
  {
    float2 w01, w23;
    w01.x = mv.x ? tv.x : NEGINF;
    w01.y = mv.y ? tv.y : NEGINF;
    w23.x = mv.z ? tv.z : NEGINF;
    w23.y = mv.w ? tv.w : NEGINF;
    *reinterpret_cast<float2 *>(&sm[HALO + j]) = w01;      // 8B-aligned
    *reinterpret_cast<float2 *>(&sm[HALO + j + 2]) = w23;  // 8B-aligned
  }
  // halo: first 14 threads fill both edges (out-of-row -> sentinel)
  if (tid < HALO) {
    const int gl = t0 - HALO + tid;
    sm[tid] = (gl >= 0) ? (mrow[gl] ? tsrow[gl] : NEGINF) : SENT;
    const int gr = t0 + TILE + tid;
    sm[TILE + HALO + tid] = (gr < N) ? (mrow[gr] ? tsrow[gr] : NEGINF) : SENT;
  }
  // softmax of width logits: ONE thread per block (last wave)
  if (tid == TPB - 1) {
    float e[15], mx = -3.4e38f;
#pragma unroll
    for (int i = 0; i < 15; ++i) {
      e[i] = wlog[i];
      mx = fmaxf(mx, e[i]);
    }
    float ssum = 0.0f;
#pragma unroll
    for (int i = 0; i < 15; ++i) {
      e[i] = expf(e[i] - mx);
      ssum += e[i];
    }
    const float inv = 1.0f / ssum;
#pragma unroll
    for (int i = 0; i < 14; ++i) swt[i] = e[i] * inv;
    swt[14] = *gamma_p;
  }
  __syncthreads();

  // ---- per-thread 32-value window (8x ds_read_b128) ----
  float A[WIN];
#pragma unroll
  for (int q = 0; q < WIN / 4; ++q) {
    const float4 v = *reinterpret_cast<const float4 *>(&sm[j + 4 * q]);
    A[4 * q + 0] = v.x;
    A[4 * q + 1] = v.y;
    A[4 * q + 2] = v.z;
    A[4 * q + 3] = v.w;
  }
  // width-1 boost: the masked scores themselves (before A is overwritten)
  float b0 = A[HALO + 0], b1 = A[HALO + 1], b2 = A[HALO + 2], b3 = A[HALO + 3];

  // ---- in-place sparse table: ascending update never reads a clobbered slot
  // level 2: A[x] = min(win[x], win[x+1])
#pragma unroll
  for (int x = 0; x < WIN - 1; ++x) A[x] = fminf(A[x], A[x + 1]);
  do_width<2>(A, swt[0], b0, b1, b2, b3);
  do_width<3>(A, swt[1], b0, b1, b2, b3);

  // level 4: A[x] = min(P2[x], P2[x+2])
#pragma unroll
  for (int x = 0; x < WIN - 3; ++x) A[x] = fminf(A[x], A[x + 2]);
  do_width<4>(A, swt[2], b0, b1, b2, b3);
  do_width<5>(A, swt[3], b0, b1, b2, b3);
  do_width<6>(A, swt[4], b0, b1, b2, b3);
  do_width<7>(A, swt[5], b0, b1, b2, b3);

  // level 8: A[x] = min(P4[x], P4[x+4])
#pragma unroll
  for (int x = 0; x < WIN - 7; ++x) A[x] = fminf(A[x], A[x + 4]);
  do_width<8>(A, swt[6], b0, b1, b2, b3);
  do_width<9>(A, swt[7], b0, b1, b2, b3);
  do_width<10>(A, swt[8], b0, b1, b2, b3);
  do_width<11>(A, swt[9], b0, b1, b2, b3);
  do_width<12>(A, swt[10], b0, b1, b2, b3);
  do_width<13>(A, swt[11], b0, b1, b2, b3);
  do_width<14>(A, swt[12], b0, b1, b2, b3);
  do_width<15>(A, swt[13], b0, b1, b2, b3);

  // ---- output: raw scores kept in registers from staging ----
  const float gamma = swt[14];
  float4 o;
  o.x = tv.x + gamma * b0;
  o.y = tv.y + gamma * b1;
  o.z = tv.z + gamma * b2;
  o.w = tv.w + gamma * b3;
  *reinterpret_cast<float4 *>(&out[(size_t)row * N + g]) = o;
}

extern "C" void kernel_launch(void *const *d_in, const int *in_sizes, int n_in,
                              void *d_out, int out_size, void *d_ws,
                              size_t ws_size, hipStream_t stream) {
  const float *ts = (const float *)d_in[0];
  const int *mask = (const int *)d_in[1];
  const float *wlog = (const float *)d_in[2];
  const float *gamma_p = (const float *)d_in[3];
  float *out = (float *)d_out;
  const int N = 8192;          // fixed problem shape (B=256, N=8192)
  const int B = in_sizes[0] / N;
  const int tiles = N / TILE;  // 8
  span_kernel<<<dim3(B * tiles), dim3(TPB), 0, stream>>>(ts, mask, wlog,
                                                         gamma_p, out, N,
                                                         tiles);
}